// Round 4
// baseline (424.841 us; speedup 1.0000x reference)
//
#include <hip/hip_runtime.h>
#include <hip/hip_bf16.h>
#include <math.h>

#define NH 16
#define NOPE 128
#define ROPE 64
#define VDIM 128
#define HD 192          // HEAD_DIM
#define SEQ 2048
#define DIM 2048
#define QKD (NH * HD)   // 3072
#define VD  (NH * VDIM) // 2048
#define QKVS 8192       // fused q|k|v row stride (shorts): [q 3072][k 3072][v 2048]

typedef __attribute__((ext_vector_type(8))) short short8;   // 8 bf16 = 4 VGPRs
typedef __attribute__((ext_vector_type(4))) short short4v;
typedef __attribute__((ext_vector_type(4))) float f32x4;
typedef unsigned int u32;

// s_waitcnt immediates (gfx9 encoding: vmcnt[3:0]@0, expcnt@4, lgkmcnt@8, vmcnt[5:4]@14)
#define WAIT_VM16 0x4F70   // vmcnt(16) (bit4 -> [5:4] field @14)
#define WAIT_VM8  0x0F78   // vmcnt(8)
#define WAIT_VM6  0x0F76   // vmcnt(6)
#define WAIT_VM0  0x0F70   // vmcnt(0)
#define WAIT_LGKM 0xC07F   // lgkmcnt(0), vmcnt/exp no-wait

static __device__ inline short f2bf(float f) {
  union { float f; unsigned u; } v; v.f = f;
  unsigned r = (v.u + 0x7fffu + ((v.u >> 16) & 1u)) >> 16;
  return (short)r;
}
static __device__ inline float bf2f(unsigned short u) {
  union { unsigned u; float f; } v; v.u = ((unsigned)u) << 16;
  return v.f;
}

// async global->LDS, 16B/lane. LDS dest = wave-uniform base + lane*16.
static __device__ __forceinline__ void gload16(const short* g, short* l) {
  __builtin_amdgcn_global_load_lds(
      (const __attribute__((address_space(1))) u32*)g,
      (__attribute__((address_space(3))) u32*)l, 16, 0, 0);
}

// ---------------------------------------------------------------------------
// 256x256 8-phase bf16 GEMM (T3+T4+T5+T1), C = A * B^T. Unchanged.
// ---------------------------------------------------------------------------

#define RDA(pp, hh, mh) do { \
  const char* Lb_ = Lsm + ((pp) * 32768) + ((hh) * 16384) + aoff; \
  afr[0] = *(const short8*)(Lb_ + ((mh) * 4096) + 0); \
  afr[1] = *(const short8*)(Lb_ + ((mh) * 4096) + 1024); \
  afr[2] = *(const short8*)(Lb_ + ((mh) * 4096) + 2048); \
  afr[3] = *(const short8*)(Lb_ + ((mh) * 4096) + 3072); \
} while (0)

#define RDB(pp, hh) do { \
  const char* Lb_ = Lsm + 65536 + ((pp) * 32768) + ((hh) * 16384) + boff; \
  bfr[0] = *(const short8*)(Lb_ + 0); \
  bfr[1] = *(const short8*)(Lb_ + 1024); \
  bfr[2] = *(const short8*)(Lb_ + 2048); \
  bfr[3] = *(const short8*)(Lb_ + 3072); \
} while (0)

#define SA(kt, h) do { \
  char* d_ = Lsm + (((kt) & 1) * 32768) + ((h) * 16384) + wv * 1024; \
  gload16(gA0 + (kt) * 64 + (h) * 32, (short*)d_); \
  gload16(gA1 + (kt) * 64 + (h) * 32, (short*)(d_ + 8192)); \
} while (0)

#define SB(kt, h) do { \
  char* d_ = Lsm + 65536 + (((kt) & 1) * 32768) + ((h) * 16384) + wv * 1024; \
  gload16(gB0 + (kt) * 64 + (h) * 32, (short*)d_); \
  gload16(gB1 + (kt) * 64 + (h) * 32, (short*)(d_ + 8192)); \
} while (0)

#define MFMA1(mi, ni) \
  acc[mi][ni] = __builtin_amdgcn_mfma_f32_16x16x32_bf16(afr[(mi) & 3], bfr[ni], acc[mi][ni], 0, 0, 0)

#define MM(mh) do { \
  MFMA1((mh)*4+0, 0); MFMA1((mh)*4+1, 0); MFMA1((mh)*4+2, 0); MFMA1((mh)*4+3, 0); \
  MFMA1((mh)*4+0, 1); MFMA1((mh)*4+1, 1); MFMA1((mh)*4+2, 1); MFMA1((mh)*4+3, 1); \
  MFMA1((mh)*4+0, 2); MFMA1((mh)*4+1, 2); MFMA1((mh)*4+2, 2); MFMA1((mh)*4+3, 2); \
  MFMA1((mh)*4+0, 3); MFMA1((mh)*4+1, 3); MFMA1((mh)*4+2, 3); MFMA1((mh)*4+3, 3); \
} while (0)

#define GBAR() __builtin_amdgcn_s_barrier()
#define GLGKM0() __builtin_amdgcn_s_waitcnt(WAIT_LGKM)
#define GPRIO1() __builtin_amdgcn_s_setprio(1)
#define GPRIO0() __builtin_amdgcn_s_setprio(0)
#define GNOP ((void)0)

#define TILE(pp, S1, S2, S3, S4, VMW) do { \
  RDA(pp, 0, 0); RDB(pp, 0); S1; \
  GBAR(); GLGKM0(); GPRIO1(); MM(0); GPRIO0(); GBAR(); \
  RDA(pp, 0, 1); S2; \
  GBAR(); GLGKM0(); GPRIO1(); MM(1); GPRIO0(); GBAR(); \
  RDA(pp, 1, 0); RDB(pp, 1); S3; \
  GBAR(); GLGKM0(); GPRIO1(); MM(0); GPRIO0(); GBAR(); \
  RDA(pp, 1, 1); S4; \
  GBAR(); GLGKM0(); GPRIO1(); MM(1); GPRIO0(); VMW; GBAR(); \
} while (0)

__global__ __launch_bounds__(512, 2) void gemm256_bt(
    const short* __restrict__ A, const short* __restrict__ B,
    short* __restrict__ C, int K, int lda, int ldb, int ldc) {
  __shared__ __align__(16) char Lsm[131072];

  const int tid = threadIdx.x;
  const int lane = tid & 63;
  const int l15 = lane & 15;
  const int quad = lane >> 4;      // 0..3
  const int wv = tid >> 6;         // 0..7
  const int wr = wv >> 2, wc = wv & 3;

  const int bid = blockIdx.x;
  const int swz = (bid & 7) * 32 + (bid >> 3);
  const int m0 = (swz >> 5) * 256;   // 8 M panels
  const int n0 = (swz & 31) * 256;   // 32 N panels

  const short* gA0 = A + (size_t)(m0 + wv * 16 + l15) * lda + quad * 8;
  const short* gA1 = gA0 + (size_t)128 * lda;
  const short* gB0 = B + (size_t)(n0 + wv * 16 + l15) * ldb + quad * 8;
  const short* gB1 = gB0 + (size_t)128 * ldb;

  const int aoff = wr * 8192 + lane * 16;
  const int boff = wc * 4096 + lane * 16;

  f32x4 acc[8][4];
#pragma unroll
  for (int i = 0; i < 8; ++i)
#pragma unroll
    for (int j = 0; j < 4; ++j) acc[i][j] = (f32x4)(0.f);
  short8 afr[4], bfr[4];

  const int NT = K >> 6;

  SB(0, 0); SA(0, 0); SB(0, 1); SA(0, 1);
  SB(1, 0); SA(1, 0); SB(1, 1);
  __builtin_amdgcn_s_waitcnt(WAIT_VM6);
  GBAR();

  int kt = 0;
  for (; kt + 4 <= NT; kt += 2) {
    TILE(0, SA(kt + 1, 1), SB(kt + 2, 0), SA(kt + 2, 0), SB(kt + 2, 1),
         __builtin_amdgcn_s_waitcnt(WAIT_VM6));
    TILE(1, SA(kt + 2, 1), SB(kt + 3, 0), SA(kt + 3, 0), SB(kt + 3, 1),
         __builtin_amdgcn_s_waitcnt(WAIT_VM6));
  }
  TILE(0, SA(kt + 1, 1), GNOP, GNOP, GNOP, __builtin_amdgcn_s_waitcnt(WAIT_VM0));
  TILE(1, GNOP, GNOP, GNOP, GNOP, GNOP);

#pragma unroll
  for (int m = 0; m < 8; ++m) {
    const size_t rb = (size_t)(m0 + wr * 128 + m * 16 + quad * 4) * ldc +
                      n0 + wc * 64 + l15;
#pragma unroll
    for (int n = 0; n < 4; ++n)
#pragma unroll
      for (int r = 0; r < 4; ++r)
        C[rb + (size_t)r * ldc + n * 16] = f2bf(acc[m][n][r]);
  }
}

// ---------------------------------------------------------------------------
// bf16 MFMA GEMM v2 (128^2): kept for the output projection.
// ---------------------------------------------------------------------------
template <bool BF16OUT>
__global__ __launch_bounds__(256) void gemm_bt(
    const short* __restrict__ A, const short* __restrict__ B,
    void* __restrict__ Cv, int K, int lda, int ldb, int ldc, float oscale) {
  __shared__ __align__(16) short Ls[4][2][4096];

  const int tid = threadIdx.x;
  const int lane = tid & 63;
  const int wave = tid >> 6;
  const int wr = wave >> 1, wc = wave & 1;
  const int lane15 = lane & 15, quad = lane >> 4;
  const int m0 = blockIdx.y * 128, n0 = blockIdx.x * 128;

  const short* gA[4]; const short* gB[4];
#pragma unroll
  for (int i = 0; i < 4; ++i) {
    int gidx = i * 64 + lane;
    int r = gidx >> 2, p = gidx & 3;
    int g = (p ^ ((r >> 1) & 3)) * 8;
    gA[i] = A + (size_t)(m0 + wr * 64 + r) * lda + g;
    gB[i] = B + (size_t)(n0 + wc * 64 + r) * ldb + g;
  }

  f32x4 acc[4][4];
#pragma unroll
  for (int i = 0; i < 4; ++i)
#pragma unroll
    for (int j = 0; j < 4; ++j) acc[i][j] = (f32x4)(0.f);

#pragma unroll
  for (int i = 0; i < 4; ++i) gload16(gA[i], &Ls[wave][0][i * 512]);
#pragma unroll
  for (int i = 0; i < 4; ++i) gload16(gB[i], &Ls[wave][0][2048 + i * 512]);

  const int rsw = (lane15 >> 1) & 3;
  for (int k0 = 0; k0 < K; k0 += 32) {
    const int cur = (k0 >> 5) & 1;
    __builtin_amdgcn_s_waitcnt(WAIT_LGKM);
    if (k0 + 32 < K) {
      const int nxt = cur ^ 1;
#pragma unroll
      for (int i = 0; i < 4; ++i) gload16(gA[i] + k0 + 32, &Ls[wave][nxt][i * 512]);
#pragma unroll
      for (int i = 0; i < 4; ++i) gload16(gB[i] + k0 + 32, &Ls[wave][nxt][2048 + i * 512]);
      __builtin_amdgcn_s_waitcnt(WAIT_VM8);
    } else {
      __builtin_amdgcn_s_waitcnt(WAIT_VM0);
    }
    const short* bufp = &Ls[wave][cur][0];
    short8 af[4], bfv[4];
#pragma unroll
    for (int i = 0; i < 4; ++i)
      af[i] = *(const short8*)&bufp[(i * 16 + lane15) * 32 + (quad ^ rsw) * 8];
#pragma unroll
    for (int j = 0; j < 4; ++j)
      bfv[j] = *(const short8*)&bufp[2048 + (j * 16 + lane15) * 32 + (quad ^ rsw) * 8];
#pragma unroll
    for (int i = 0; i < 4; ++i)
#pragma unroll
      for (int j = 0; j < 4; ++j)
        acc[i][j] = __builtin_amdgcn_mfma_f32_16x16x32_bf16(af[i], bfv[j], acc[i][j], 0, 0, 0);
  }

#pragma unroll
  for (int i = 0; i < 4; ++i)
#pragma unroll
    for (int j = 0; j < 4; ++j)
#pragma unroll
      for (int r = 0; r < 4; ++r) {
        size_t idx = (size_t)(m0 + wr * 64 + i * 16 + quad * 4 + r) * ldc +
                     n0 + wc * 64 + j * 16 + lane15;
        if (BF16OUT)
          ((short*)Cv)[idx] = f2bf(acc[i][j][r] * oscale);
        else
          ((float*)Cv)[idx] = acc[i][j][r];
      }
}

// ---------------------------------------------------------------------------
// RoPE in-place on fused qkv bf16 [SEQ][QKVS].
// ---------------------------------------------------------------------------
__global__ __launch_bounds__(256) void rope_qk(
    short* __restrict__ qk, const float* __restrict__ cosf, const float* __restrict__ sinf) {
  int idx = blockIdx.x * blockDim.x + threadIdx.x;
  int j = idx & 31;
  int h = (idx >> 5) & (NH - 1);
  int s = idx >> 9;
  if (s >= SEQ) return;

  float c = cosf[s * 32 + j];
  float sn = sinf[s * 32 + j];
  size_t rowb = (size_t)s * QKVS + h * HD + NOPE + 2 * j;

  u32* pq = (u32*)(qk + rowb);
  u32 w = *pq;
  float a = bf2f((unsigned short)(w & 0xffff));
  float b = bf2f((unsigned short)(w >> 16));
  *pq = (u32)(unsigned short)f2bf(a * c - b * sn) |
        ((u32)(unsigned short)f2bf(a * sn + b * c) << 16);

  u32* pk = (u32*)(qk + rowb + QKD);
  w = *pk;
  a = bf2f((unsigned short)(w & 0xffff));
  b = bf2f((unsigned short)(w >> 16));
  *pk = (u32)(unsigned short)f2bf(a * c - b * sn) |
        ((u32)(unsigned short)f2bf(a * sn + b * c) << 16);
}

// ---------------------------------------------------------------------------
// Converts.
// ---------------------------------------------------------------------------
__global__ __launch_bounds__(256) void bf16_convert(
    const float* __restrict__ in, short* __restrict__ out, int n4) {
  int i = blockIdx.x * 256 + threadIdx.x;
  if (i >= n4) return;
  float4 f = ((const float4*)in)[i];
  short4v o;
  o.x = f2bf(f.x); o.y = f2bf(f.y); o.z = f2bf(f.z); o.w = f2bf(f.w);
  ((short4v*)out)[i] = o;
}

__global__ __launch_bounds__(256) void conv_wqkv(
    const float* __restrict__ wq, const float* __restrict__ wk,
    const float* __restrict__ wv, short* __restrict__ wqkv, int n4) {
  int i = blockIdx.x * 256 + threadIdx.x;
  if (i >= n4) return;
  int row = i >> 9;
  float4 f;
  if (row < QKD) f = ((const float4*)wq)[i];
  else if (row < 2 * QKD) f = ((const float4*)wk)[i - QKD * (DIM / 4)];
  else f = ((const float4*)wv)[i - 2 * QKD * (DIM / 4)];
  short4v o;
  o.x = f2bf(f.x); o.y = f2bf(f.y); o.z = f2bf(f.z); o.w = f2bf(f.w);
  ((short4v*)wqkv)[i] = o;
}

// ---------------------------------------------------------------------------
// v bf16 -> vtb bf16 [h][d][t] transpose.
// ---------------------------------------------------------------------------
__global__ __launch_bounds__(256) void vt_bf16(
    const short* __restrict__ vb, short* __restrict__ vtb) {
  __shared__ short tile[64][74];
  const int t0 = blockIdx.x * 64;
  const int c0 = blockIdx.y * 64;
  const int tid = threadIdx.x;
#pragma unroll
  for (int i = 0; i < 16; ++i) {
    int idx = i * 256 + tid;
    int r = idx >> 6, c = idx & 63;
    tile[r][c] = vb[(size_t)(t0 + r) * QKVS + c0 + c];
  }
  __syncthreads();
  const int h = c0 >> 7;
  const int dbase = c0 & 127;
#pragma unroll
  for (int i = 0; i < 16; ++i) {
    int idx = i * 256 + tid;
    int d = idx >> 6, t = idx & 63;
    vtb[(size_t)h * VDIM * SEQ + (size_t)(dbase + d) * SEQ + t0 + t] = tile[t][d];
  }
}

// ---------------------------------------------------------------------------
// Split-T flash attention v3: wave-autonomous V, 2 barriers/tile.
//  - V NEVER in LDS: each wave loads its PV B-fragments directly from vtb
//    (16 x short8 per tile, L2-resident via head clustering) into 64 VGPRs;
//    waits only on its own vmcnt.
//  - K shared in LDS, single-buffered; per tile: QK -> barrier(readers done)
//    -> issue K(t+1) -> softmax (covers K) -> vmcnt(6) proves V(t) -> PV
//    -> issue V(t+1) -> vmcnt(16) proves K(t+1) -> barrier.
//  - Heavy-blocks-first dispatch (qt reversed) kills the imbalance tail.
// LDS: 24576 (K) + 9728 (Ps) = 34304 B -> 3 blocks/CU (VGPR-capped, lb(256,3)).
// ---------------------------------------------------------------------------
#define BQ 64
#define BT 64
#define CHT 8
#define PSTR 76
#define MFIX 8.0f

__global__ __launch_bounds__(256, 3) void attn_part(
    const short* __restrict__ qk,   // [SEQ][QKVS] bf16
    const short* __restrict__ vtb,  // [NH][VDIM][SEQ] bf16
    short* __restrict__ Opart,      // [1280][64][128] bf16
    float* __restrict__ lpart)      // [1280][64] fp32
{
  __shared__ __align__(16) short Ks[BT * 192];     // 24576 B
  __shared__ __align__(16) short Ps[4 * 16 * PSTR];

  // XCD head-clustering decode + heavy-first qt order
  const int bid = blockIdx.x;
  const int i0 = bid >> 3;                       // 0..255 within XCD
  const int h = (bid & 7) + ((i0 >> 7) << 3);    // heads {xcd, xcd+8}
  const int qt = 31 - ((i0 & 127) >> 2);         // 31..0 (heavy blocks first)
  const int chk = i0 & 3;                        // 0..3
  if (chk * CHT > qt) return;

  const int tid = threadIdx.x;
  const int wave = tid >> 6;
  const int lane = tid & 63;
  const int lane15 = lane & 15;
  const int quad = lane >> 4;
  const int bb = qt >> 3;
  const int slot = h * 80 + qt + 4 * bb * (bb - 1) + (qt - 8 * bb) * bb + chk;
  const int R0 = qt * BQ;
  const int kt_beg = chk * CHT;
  const int kt_end = min(kt_beg + CHT, qt + 1);
  const float scale = 0.072168784f;  // 1/sqrt(192)

  // Q A-frags (6 global loads -> in the vmcnt ledger, pinned before staging)
  const int qrow = R0 + wave * 16 + lane15;
  short8 qf[6];
  const short* qbase = qk + (size_t)qrow * QKVS + h * HD + quad * 8;
#pragma unroll
  for (int kc = 0; kc < 6; ++kc) qf[kc] = *(const short8*)(qbase + kc * 32);
  __builtin_amdgcn_sched_barrier(0);

  // K staging descriptors (XOR-swizzled, cooperative)
  const short* kb = qk + QKD;
  int lKoff[6]; const short* gK[6];
#pragma unroll
  for (int i = 0; i < 6; ++i) {
    int id = i * 256 + tid;
    int row = id / 24, cX = id - row * 24;
    int ch = cX ^ (row & 7);
    lKoff[i] = id * 8;
    gK[i] = kb + (size_t)row * QKVS + h * HD + ch * 8;
  }

  // per-lane V fragment base: vf[ch][half] = vtb[h*128+ch*16+l15][t0+half*32+quad*8]
  const short* vbase = vtb + ((size_t)(h * VDIM + lane15) * SEQ) + quad * 8;

  f32x4 oacc[8];
#pragma unroll
  for (int i = 0; i < 8; ++i) oacc[i] = (f32x4)(0.f);
  float lsum[4] = {0.f, 0.f, 0.f, 0.f};
  short8 vreg[8][2];

  short* pw = &Ps[wave * 16 * PSTR];

  // prologue: issue K(kt_beg) coop (6), V(kt_beg) per-wave (16).
  // queue = [Q6, K6, V16] = 28 -> vmcnt(16) proves Q+K; V stays in flight.
  {
    const size_t t0 = (size_t)kt_beg * BT;
#pragma unroll
    for (int i = 0; i < 6; ++i) gload16(gK[i] + t0 * QKVS, &Ks[lKoff[i]]);
#pragma unroll
    for (int ch = 0; ch < 8; ++ch)
#pragma unroll
      for (int hf = 0; hf < 2; ++hf)
        vreg[ch][hf] = *(const short8*)(vbase + (size_t)ch * 16 * SEQ + t0 + hf * 32);
  }
  __builtin_amdgcn_s_waitcnt(WAIT_VM16);
  __builtin_amdgcn_s_barrier();
  __builtin_amdgcn_sched_barrier(0);

  for (int kt = kt_beg; kt < kt_end; ++kt) {
    const bool have = (kt + 1 < kt_end);

    // S = Q K^T on Ks
    f32x4 sacc[4];
    __builtin_amdgcn_s_setprio(1);
#pragma unroll
    for (int c = 0; c < 4; ++c) {
      sacc[c] = (f32x4)(0.f);
      const int row = c * 16 + lane15;
#pragma unroll
      for (int kc = 0; kc < 6; ++kc) {
        int cX = (4 * kc + quad) ^ (lane15 & 7);
        short8 kf = *(const short8*)&Ks[row * 192 + cX * 8];
        sacc[c] = __builtin_amdgcn_mfma_f32_16x16x32_bf16(qf[kc], kf, sacc[c], 0, 0, 0);
      }
    }
    __builtin_amdgcn_s_setprio(0);

    // all waves done reading Ks -> safe to overwrite
    __builtin_amdgcn_s_barrier();
    __builtin_amdgcn_sched_barrier(0);

    // issue K(kt+1) into Ks (covered by softmax+PV below)
    if (have) {
      const size_t tn = (size_t)(kt + 1) * BT;
#pragma unroll
      for (int i = 0; i < 6; ++i) gload16(gK[i] + tn * QKVS, &Ks[lKoff[i]]);
    }

    if (kt == qt) {  // diagonal tile mask
#pragma unroll
      for (int c = 0; c < 4; ++c)
#pragma unroll
        for (int r = 0; r < 4; ++r) {
          int tloc = c * 16 + lane15;
          int qloc = wave * 16 + quad * 4 + r;
          if (tloc > qloc) sacc[c][r] = -1e30f;
        }
    }

    // P = exp(S*scale - MFIX); partial row sums; stage P bf16 (wave-local)
#pragma unroll
    for (int c = 0; c < 4; ++c)
#pragma unroll
      for (int r = 0; r < 4; ++r) {
        float p = __expf(sacc[c][r] * scale - MFIX);
        lsum[r] += p;
        pw[(quad * 4 + r) * PSTR + c * 16 + lane15] = f2bf(p);
      }

    short8 pf0 = *(const short8*)&pw[lane15 * PSTR + quad * 8];
    short8 pf1 = *(const short8*)&pw[lane15 * PSTR + 32 + quad * 8];

    // prove V(kt) regs landed: queue = [V16, K6] -> vmcnt(6); last iter: [V16] -> vmcnt(0)
    if (have) __builtin_amdgcn_s_waitcnt(WAIT_VM6);
    else      __builtin_amdgcn_s_waitcnt(WAIT_VM0);
    __builtin_amdgcn_sched_barrier(0);

    // PV from registers (no LDS)
    __builtin_amdgcn_s_setprio(1);
#pragma unroll
    for (int ch = 0; ch < 8; ++ch) {
      oacc[ch] = __builtin_amdgcn_mfma_f32_16x16x32_bf16(pf0, vreg[ch][0], oacc[ch], 0, 0, 0);
      oacc[ch] = __builtin_amdgcn_mfma_f32_16x16x32_bf16(pf1, vreg[ch][1], oacc[ch], 0, 0, 0);
    }
    __builtin_amdgcn_s_setprio(0);
    __builtin_amdgcn_sched_barrier(0);

    if (have) {
      // issue V(kt+1) per-wave (WAR on vreg safe: loads issued after PV)
      const size_t tn = (size_t)(kt + 1) * BT;
#pragma unroll
      for (int ch = 0; ch < 8; ++ch)
#pragma unroll
        for (int hf = 0; hf < 2; ++hf)
          vreg[ch][hf] = *(const short8*)(vbase + (size_t)ch * 16 * SEQ + tn + hf * 32);
      // prove K(kt+1): queue = [K6, V16] -> vmcnt(16); then block-wide ready
      __builtin_amdgcn_s_waitcnt(WAIT_VM16);
      __builtin_amdgcn_s_barrier();
      __builtin_amdgcn_sched_barrier(0);
    }
  }

  // epilogue: write unnormalized partials
  short* op = Opart + (size_t)slot * (64 * 128);
#pragma unroll
  for (int ch = 0; ch < 8; ++ch)
#pragma unroll
    for (int r = 0; r < 4; ++r)
      op[(wave * 16 + quad * 4 + r) * 128 + ch * 16 + lane15] = f2bf(oacc[ch][r]);

  float red[4];
#pragma unroll
  for (int r = 0; r < 4; ++r) {
    float s = lsum[r];
    s += __shfl_xor(s, 1, 64);
    s += __shfl_xor(s, 2, 64);
    s += __shfl_xor(s, 4, 64);
    s += __shfl_xor(s, 8, 64);
    red[r] = s;
  }
  if (lane15 == 0) {
#pragma unroll
    for (int r = 0; r < 4; ++r)
      lpart[(size_t)slot * 64 + wave * 16 + quad * 4 + r] = red[r];
  }
}

// ---------------------------------------------------------------------------
// Phase B: sum chunk partials, normalize, write aob (into v-cols of qkv).
// ---------------------------------------------------------------------------
__global__ __launch_bounds__(256) void attn_combine(
    const short* __restrict__ Opart, const float* __restrict__ lpart,
    short* __restrict__ aob) {   // aob = qkv + 6144, row stride QKVS
  const int qt = blockIdx.x, h = blockIdx.y;
  const int nact = (qt >> 3) + 1;
  const int bb = qt >> 3;
  const int base = h * 80 + qt + 4 * bb * (bb - 1) + (qt - 8 * bb) * bb;
  const int tid = threadIdx.x;
  const int row = tid >> 2;
  const int cg = (tid & 3) * 32;

  float acc[32];
#pragma unroll
  for (int e = 0; e < 32; ++e) acc[e] = 0.f;
  float lsum = 0.f;

  for (int c = 0; c < nact; ++c) {
    const short* sp = Opart + (size_t)(base + c) * (64 * 128) + row * 128 + cg;
    lsum += lpart[(size_t)(base + c) * 64 + row];
#pragma unroll
    for (int g = 0; g < 4; ++g) {
      short8 vv = *(const short8*)(sp + g * 8);
#pragma unroll
      for (int e = 0; e < 8; ++e) acc[g * 8 + e] += bf2f((unsigned short)vv[e]);
    }
  }

  float inv = 1.f / lsum;
#pragma unroll
  for (int g = 0; g < 4; ++g) {
    short8 ov;
#pragma unroll
    for (int e = 0; e < 8; ++e) ov[e] = f2bf(acc[g * 8 + e] * inv);
    *(short8*)(aob + (size_t)(qt * 64 + row) * QKVS + h * 128 + cg + g * 8) = ov;
  }
}

// ---------------------------------------------------------------------------
// Workspace (bytes), peak 75,497,472 (< proven 79,691,776):
//   [0,        8388608)  xb  -> wo_b (after qkv gemm)
//   [8388608, 41943040)  wqkv -> {vtb@8388608, Opart@16777216, lpart@37748736}
//   [41943040,75497472)  qkv bf16 [2048][8192]; aob lives in v-cols (6144+)
// ---------------------------------------------------------------------------
extern "C" void kernel_launch(void* const* d_in, const int* in_sizes, int n_in,
                              void* d_out, int out_size, void* d_ws, size_t ws_size,
                              hipStream_t stream) {
  const float* x  = (const float*)d_in[0];
  const float* wq = (const float*)d_in[1];
  const float* wk = (const float*)d_in[2];
  const float* wv = (const float*)d_in[3];
  const float* wo = (const float*)d_in[4];
  const float* fc = (const float*)d_in[5];
  const float* fs = (const float*)d_in[6];

  char* ws8 = (char*)d_ws;
  short* xb    = (short*)(ws8 + 0);
  short* wo_b  = (short*)(ws8 + 0);
  short* wqkv  = (short*)(ws8 + 8388608);
  short* vtb   = (short*)(ws8 + 8388608);
  short* Opart = (short*)(ws8 + 16777216);
  float* lpart = (float*)(ws8 + 37748736);
  short* qkv   = (short*)(ws8 + 41943040);
  float* out   = (float*)d_out;

  const int NX4 = DIM * DIM / 4;
  const int NQKV4 = QKVS * DIM / 4;
  const int ROPE_GRID = (SEQ * NH * 32) / 256;

  bf16_convert<<<(NX4 + 255) / 256, 256, 0, stream>>>(x, xb, NX4);
  conv_wqkv<<<(NQKV4 + 255) / 256, 256, 0, stream>>>(wq, wk, wv, wqkv, NQKV4);

  // fused QKV projection: qkv [2048][8192] via 256^2 8-phase kernel.
  gemm256_bt<<<dim3((QKVS / 256) * (SEQ / 256)), 512, 0, stream>>>(
      xb, wqkv, qkv, DIM, DIM, DIM, QKVS);
  rope_qk<<<ROPE_GRID, 256, 0, stream>>>(qkv, fc, fs);
  vt_bf16<<<dim3(SEQ / 64, VD / 64), 256, 0, stream>>>(qkv + 2 * QKD, vtb);

  // wo convert (xb dead after qkv gemm)
  bf16_convert<<<(NX4 + 255) / 256, 256, 0, stream>>>(wo, wo_b, NX4);

  // split-T attention: 1D grid 2048 = 32qt * 16h * 4chk, XCD-decoded in-kernel
  attn_part<<<dim3(2048), 256, 0, stream>>>(qkv, vtb, Opart, lpart);
  attn_combine<<<dim3(SEQ / BQ, NH), 256, 0, stream>>>(Opart, lpart, qkv + 2 * QKD);

  // output projection (A = aob in v-cols, lda = QKVS)
  gemm_bt<false><<<dim3(DIM / 128, SEQ / 128), 256, 0, stream>>>(
      qkv + 2 * QKD, wo_b, out, DIM, QKVS, DIM, DIM, 1.0f);
}

// Round 5
// 329.579 us; speedup vs baseline: 1.2890x; 1.2890x over previous
//
#include <hip/hip_runtime.h>
#include <hip/hip_bf16.h>
#include <math.h>

#define NH 16
#define NOPE 128
#define ROPE 64
#define VDIM 128
#define HD 192          // HEAD_DIM
#define SEQ 2048
#define DIM 2048
#define QKD (NH * HD)   // 3072
#define VD  (NH * VDIM) // 2048
#define QKVS 8192       // fused q|k|v row stride (shorts): [q 3072][k 3072][v 2048]

typedef __attribute__((ext_vector_type(8))) short short8;   // 8 bf16 = 4 VGPRs
typedef __attribute__((ext_vector_type(4))) short short4v;
typedef __attribute__((ext_vector_type(4))) float f32x4;
typedef unsigned int u32;

// s_waitcnt immediates (gfx9 encoding: vmcnt[3:0]@0, expcnt@4, lgkmcnt@8, vmcnt[5:4]@14)
#define WAIT_VM8  0x0F78   // vmcnt(8)
#define WAIT_VM6  0x0F76   // vmcnt(6)
#define WAIT_VM0  0x0F70   // vmcnt(0)
#define WAIT_LGKM 0xC07F   // lgkmcnt(0), vmcnt/exp no-wait

static __device__ inline short f2bf(float f) {
  union { float f; unsigned u; } v; v.f = f;
  unsigned r = (v.u + 0x7fffu + ((v.u >> 16) & 1u)) >> 16;
  return (short)r;
}
static __device__ inline float bf2f(unsigned short u) {
  union { unsigned u; float f; } v; v.u = ((unsigned)u) << 16;
  return v.f;
}

// async global->LDS, 16B/lane. LDS dest = wave-uniform base + lane*16.
static __device__ __forceinline__ void gload16(const short* g, short* l) {
  __builtin_amdgcn_global_load_lds(
      (const __attribute__((address_space(1))) u32*)g,
      (__attribute__((address_space(3))) u32*)l, 16, 0, 0);
}

// ---------------------------------------------------------------------------
// 256x256 8-phase bf16 GEMM (T3+T4+T5+T1), C = A * B^T. Unchanged.
// ---------------------------------------------------------------------------

#define RDA(pp, hh, mh) do { \
  const char* Lb_ = Lsm + ((pp) * 32768) + ((hh) * 16384) + aoff; \
  afr[0] = *(const short8*)(Lb_ + ((mh) * 4096) + 0); \
  afr[1] = *(const short8*)(Lb_ + ((mh) * 4096) + 1024); \
  afr[2] = *(const short8*)(Lb_ + ((mh) * 4096) + 2048); \
  afr[3] = *(const short8*)(Lb_ + ((mh) * 4096) + 3072); \
} while (0)

#define RDB(pp, hh) do { \
  const char* Lb_ = Lsm + 65536 + ((pp) * 32768) + ((hh) * 16384) + boff; \
  bfr[0] = *(const short8*)(Lb_ + 0); \
  bfr[1] = *(const short8*)(Lb_ + 1024); \
  bfr[2] = *(const short8*)(Lb_ + 2048); \
  bfr[3] = *(const short8*)(Lb_ + 3072); \
} while (0)

#define SA(kt, h) do { \
  char* d_ = Lsm + (((kt) & 1) * 32768) + ((h) * 16384) + wv * 1024; \
  gload16(gA0 + (kt) * 64 + (h) * 32, (short*)d_); \
  gload16(gA1 + (kt) * 64 + (h) * 32, (short*)(d_ + 8192)); \
} while (0)

#define SB(kt, h) do { \
  char* d_ = Lsm + 65536 + (((kt) & 1) * 32768) + ((h) * 16384) + wv * 1024; \
  gload16(gB0 + (kt) * 64 + (h) * 32, (short*)d_); \
  gload16(gB1 + (kt) * 64 + (h) * 32, (short*)(d_ + 8192)); \
} while (0)

#define MFMA1(mi, ni) \
  acc[mi][ni] = __builtin_amdgcn_mfma_f32_16x16x32_bf16(afr[(mi) & 3], bfr[ni], acc[mi][ni], 0, 0, 0)

#define MM(mh) do { \
  MFMA1((mh)*4+0, 0); MFMA1((mh)*4+1, 0); MFMA1((mh)*4+2, 0); MFMA1((mh)*4+3, 0); \
  MFMA1((mh)*4+0, 1); MFMA1((mh)*4+1, 1); MFMA1((mh)*4+2, 1); MFMA1((mh)*4+3, 1); \
  MFMA1((mh)*4+0, 2); MFMA1((mh)*4+1, 2); MFMA1((mh)*4+2, 2); MFMA1((mh)*4+3, 2); \
  MFMA1((mh)*4+0, 3); MFMA1((mh)*4+1, 3); MFMA1((mh)*4+2, 3); MFMA1((mh)*4+3, 3); \
} while (0)

#define GBAR() __builtin_amdgcn_s_barrier()
#define GLGKM0() __builtin_amdgcn_s_waitcnt(WAIT_LGKM)
#define GPRIO1() __builtin_amdgcn_s_setprio(1)
#define GPRIO0() __builtin_amdgcn_s_setprio(0)
#define GNOP ((void)0)

#define TILE(pp, S1, S2, S3, S4, VMW) do { \
  RDA(pp, 0, 0); RDB(pp, 0); S1; \
  GBAR(); GLGKM0(); GPRIO1(); MM(0); GPRIO0(); GBAR(); \
  RDA(pp, 0, 1); S2; \
  GBAR(); GLGKM0(); GPRIO1(); MM(1); GPRIO0(); GBAR(); \
  RDA(pp, 1, 0); RDB(pp, 1); S3; \
  GBAR(); GLGKM0(); GPRIO1(); MM(0); GPRIO0(); GBAR(); \
  RDA(pp, 1, 1); S4; \
  GBAR(); GLGKM0(); GPRIO1(); MM(1); GPRIO0(); VMW; GBAR(); \
} while (0)

__global__ __launch_bounds__(512, 2) void gemm256_bt(
    const short* __restrict__ A, const short* __restrict__ B,
    short* __restrict__ C, int K, int lda, int ldb, int ldc) {
  __shared__ __align__(16) char Lsm[131072];

  const int tid = threadIdx.x;
  const int lane = tid & 63;
  const int l15 = lane & 15;
  const int quad = lane >> 4;      // 0..3
  const int wv = tid >> 6;         // 0..7
  const int wr = wv >> 2, wc = wv & 3;

  const int bid = blockIdx.x;
  const int swz = (bid & 7) * 32 + (bid >> 3);
  const int m0 = (swz >> 5) * 256;   // 8 M panels
  const int n0 = (swz & 31) * 256;   // 32 N panels

  const short* gA0 = A + (size_t)(m0 + wv * 16 + l15) * lda + quad * 8;
  const short* gA1 = gA0 + (size_t)128 * lda;
  const short* gB0 = B + (size_t)(n0 + wv * 16 + l15) * ldb + quad * 8;
  const short* gB1 = gB0 + (size_t)128 * ldb;

  const int aoff = wr * 8192 + lane * 16;
  const int boff = wc * 4096 + lane * 16;

  f32x4 acc[8][4];
#pragma unroll
  for (int i = 0; i < 8; ++i)
#pragma unroll
    for (int j = 0; j < 4; ++j) acc[i][j] = (f32x4)(0.f);
  short8 afr[4], bfr[4];

  const int NT = K >> 6;

  SB(0, 0); SA(0, 0); SB(0, 1); SA(0, 1);
  SB(1, 0); SA(1, 0); SB(1, 1);
  __builtin_amdgcn_s_waitcnt(WAIT_VM6);
  GBAR();

  int kt = 0;
  for (; kt + 4 <= NT; kt += 2) {
    TILE(0, SA(kt + 1, 1), SB(kt + 2, 0), SA(kt + 2, 0), SB(kt + 2, 1),
         __builtin_amdgcn_s_waitcnt(WAIT_VM6));
    TILE(1, SA(kt + 2, 1), SB(kt + 3, 0), SA(kt + 3, 0), SB(kt + 3, 1),
         __builtin_amdgcn_s_waitcnt(WAIT_VM6));
  }
  TILE(0, SA(kt + 1, 1), GNOP, GNOP, GNOP, __builtin_amdgcn_s_waitcnt(WAIT_VM0));
  TILE(1, GNOP, GNOP, GNOP, GNOP, GNOP);

#pragma unroll
  for (int m = 0; m < 8; ++m) {
    const size_t rb = (size_t)(m0 + wr * 128 + m * 16 + quad * 4) * ldc +
                      n0 + wc * 64 + l15;
#pragma unroll
    for (int n = 0; n < 4; ++n)
#pragma unroll
      for (int r = 0; r < 4; ++r)
        C[rb + (size_t)r * ldc + n * 16] = f2bf(acc[m][n][r]);
  }
}

// ---------------------------------------------------------------------------
// bf16 MFMA GEMM v2 (128^2): kept for the output projection.
// ---------------------------------------------------------------------------
template <bool BF16OUT>
__global__ __launch_bounds__(256) void gemm_bt(
    const short* __restrict__ A, const short* __restrict__ B,
    void* __restrict__ Cv, int K, int lda, int ldb, int ldc, float oscale) {
  __shared__ __align__(16) short Ls[4][2][4096];

  const int tid = threadIdx.x;
  const int lane = tid & 63;
  const int wave = tid >> 6;
  const int wr = wave >> 1, wc = wave & 1;
  const int lane15 = lane & 15, quad = lane >> 4;
  const int m0 = blockIdx.y * 128, n0 = blockIdx.x * 128;

  const short* gA[4]; const short* gB[4];
#pragma unroll
  for (int i = 0; i < 4; ++i) {
    int gidx = i * 64 + lane;
    int r = gidx >> 2, p = gidx & 3;
    int g = (p ^ ((r >> 1) & 3)) * 8;
    gA[i] = A + (size_t)(m0 + wr * 64 + r) * lda + g;
    gB[i] = B + (size_t)(n0 + wc * 64 + r) * ldb + g;
  }

  f32x4 acc[4][4];
#pragma unroll
  for (int i = 0; i < 4; ++i)
#pragma unroll
    for (int j = 0; j < 4; ++j) acc[i][j] = (f32x4)(0.f);

#pragma unroll
  for (int i = 0; i < 4; ++i) gload16(gA[i], &Ls[wave][0][i * 512]);
#pragma unroll
  for (int i = 0; i < 4; ++i) gload16(gB[i], &Ls[wave][0][2048 + i * 512]);

  const int rsw = (lane15 >> 1) & 3;
  for (int k0 = 0; k0 < K; k0 += 32) {
    const int cur = (k0 >> 5) & 1;
    __builtin_amdgcn_s_waitcnt(WAIT_LGKM);
    if (k0 + 32 < K) {
      const int nxt = cur ^ 1;
#pragma unroll
      for (int i = 0; i < 4; ++i) gload16(gA[i] + k0 + 32, &Ls[wave][nxt][i * 512]);
#pragma unroll
      for (int i = 0; i < 4; ++i) gload16(gB[i] + k0 + 32, &Ls[wave][nxt][2048 + i * 512]);
      __builtin_amdgcn_s_waitcnt(WAIT_VM8);
    } else {
      __builtin_amdgcn_s_waitcnt(WAIT_VM0);
    }
    const short* bufp = &Ls[wave][cur][0];
    short8 af[4], bfv[4];
#pragma unroll
    for (int i = 0; i < 4; ++i)
      af[i] = *(const short8*)&bufp[(i * 16 + lane15) * 32 + (quad ^ rsw) * 8];
#pragma unroll
    for (int j = 0; j < 4; ++j)
      bfv[j] = *(const short8*)&bufp[2048 + (j * 16 + lane15) * 32 + (quad ^ rsw) * 8];
#pragma unroll
    for (int i = 0; i < 4; ++i)
#pragma unroll
      for (int j = 0; j < 4; ++j)
        acc[i][j] = __builtin_amdgcn_mfma_f32_16x16x32_bf16(af[i], bfv[j], acc[i][j], 0, 0, 0);
  }

#pragma unroll
  for (int i = 0; i < 4; ++i)
#pragma unroll
    for (int j = 0; j < 4; ++j)
#pragma unroll
      for (int r = 0; r < 4; ++r) {
        size_t idx = (size_t)(m0 + wr * 64 + i * 16 + quad * 4 + r) * ldc +
                     n0 + wc * 64 + j * 16 + lane15;
        if (BF16OUT)
          ((short*)Cv)[idx] = f2bf(acc[i][j][r] * oscale);
        else
          ((float*)Cv)[idx] = acc[i][j][r];
      }
}

// ---------------------------------------------------------------------------
// RoPE in-place on fused qkv bf16 [SEQ][QKVS].
// ---------------------------------------------------------------------------
__global__ __launch_bounds__(256) void rope_qk(
    short* __restrict__ qk, const float* __restrict__ cosf, const float* __restrict__ sinf) {
  int idx = blockIdx.x * blockDim.x + threadIdx.x;
  int j = idx & 31;
  int h = (idx >> 5) & (NH - 1);
  int s = idx >> 9;
  if (s >= SEQ) return;

  float c = cosf[s * 32 + j];
  float sn = sinf[s * 32 + j];
  size_t rowb = (size_t)s * QKVS + h * HD + NOPE + 2 * j;

  u32* pq = (u32*)(qk + rowb);
  u32 w = *pq;
  float a = bf2f((unsigned short)(w & 0xffff));
  float b = bf2f((unsigned short)(w >> 16));
  *pq = (u32)(unsigned short)f2bf(a * c - b * sn) |
        ((u32)(unsigned short)f2bf(a * sn + b * c) << 16);

  u32* pk = (u32*)(qk + rowb + QKD);
  w = *pk;
  a = bf2f((unsigned short)(w & 0xffff));
  b = bf2f((unsigned short)(w >> 16));
  *pk = (u32)(unsigned short)f2bf(a * c - b * sn) |
        ((u32)(unsigned short)f2bf(a * sn + b * c) << 16);
}

// ---------------------------------------------------------------------------
// Converts.
// ---------------------------------------------------------------------------
__global__ __launch_bounds__(256) void bf16_convert(
    const float* __restrict__ in, short* __restrict__ out, int n4) {
  int i = blockIdx.x * 256 + threadIdx.x;
  if (i >= n4) return;
  float4 f = ((const float4*)in)[i];
  short4v o;
  o.x = f2bf(f.x); o.y = f2bf(f.y); o.z = f2bf(f.z); o.w = f2bf(f.w);
  ((short4v*)out)[i] = o;
}

__global__ __launch_bounds__(256) void conv_wqkv(
    const float* __restrict__ wq, const float* __restrict__ wk,
    const float* __restrict__ wv, short* __restrict__ wqkv, int n4) {
  int i = blockIdx.x * 256 + threadIdx.x;
  if (i >= n4) return;
  int row = i >> 9;
  float4 f;
  if (row < QKD) f = ((const float4*)wq)[i];
  else if (row < 2 * QKD) f = ((const float4*)wk)[i - QKD * (DIM / 4)];
  else f = ((const float4*)wv)[i - 2 * QKD * (DIM / 4)];
  short4v o;
  o.x = f2bf(f.x); o.y = f2bf(f.y); o.z = f2bf(f.z); o.w = f2bf(f.w);
  ((short4v*)wqkv)[i] = o;
}

// ---------------------------------------------------------------------------
// v bf16 -> vtb bf16 [h][d][t] transpose.
// ---------------------------------------------------------------------------
__global__ __launch_bounds__(256) void vt_bf16(
    const short* __restrict__ vb, short* __restrict__ vtb) {
  __shared__ short tile[64][74];
  const int t0 = blockIdx.x * 64;
  const int c0 = blockIdx.y * 64;
  const int tid = threadIdx.x;
#pragma unroll
  for (int i = 0; i < 16; ++i) {
    int idx = i * 256 + tid;
    int r = idx >> 6, c = idx & 63;
    tile[r][c] = vb[(size_t)(t0 + r) * QKVS + c0 + c];
  }
  __syncthreads();
  const int h = c0 >> 7;
  const int dbase = c0 & 127;
#pragma unroll
  for (int i = 0; i < 16; ++i) {
    int idx = i * 256 + tid;
    int d = idx >> 6, t = idx & 63;
    vtb[(size_t)h * VDIM * SEQ + (size_t)(dbase + d) * SEQ + t0 + t] = tile[t][d];
  }
}

// ---------------------------------------------------------------------------
// Split-T flash attention v4: BQ=128 via 8 waves (512 thr), R1-proven inner
// loop. Each staged 64x(192+128) K/V tile now feeds 128 Q rows (2x reuse);
// block-tiles drop 8448 -> 4352. Grid (8,80): xcd = blockIdx.x owns heads
// {xcd, xcd+8}; heavy-first chunk decode; zero dead blocks.
// LDS: 24576 (K) + 16384 (V) + 19456 (Ps, 8 waves) = 60416 -> 2 blocks/CU
// (16 waves/CU). VGPR ~88 (cap 128 via lb(512,4)).
// Slots: per head 40 chunks: S(qtb) = (g+1)*(2g+r), g=qtb>>2, r=qtb&3.
// ---------------------------------------------------------------------------
#define BQ 128
#define BT 64
#define CHT 8
#define PSTR 76
#define MFIX 8.0f

__global__ __launch_bounds__(512, 4) void attn_part(
    const short* __restrict__ qk,   // [SEQ][QKVS] bf16
    const short* __restrict__ vtb,  // [NH][VDIM][SEQ] bf16
    short* __restrict__ Opart,      // [640][128][128] bf16
    float* __restrict__ lpart)      // [640][128] fp32
{
  __shared__ __align__(16) short Ks[BT * 192];      // 24576 B
  __shared__ __align__(16) short Vt[VDIM * BT];     // 16384 B
  __shared__ __align__(16) short Ps[8 * 16 * PSTR]; // 19456 B

  // decode: xcd owns heads {xcd, xcd+8}; heavy qt-blocks first.
  const int xcd = blockIdx.x;          // 0..7
  const int i0 = blockIdx.y;           // 0..79
  const int h = xcd + ((i0 >= 40) ? 8 : 0);
  int jj = (i0 >= 40) ? (i0 - 40) : i0;  // 0..39
  int qtb = 15;
  while (jj >= (qtb >> 2) + 1) { jj -= (qtb >> 2) + 1; --qtb; }
  const int chk = jj;                   // 0..(qtb>>2)

  const int tid = threadIdx.x;
  const int wave = tid >> 6;            // 0..7
  const int lane = tid & 63;
  const int lane15 = lane & 15;
  const int quad = lane >> 4;
  const int g = qtb >> 2;
  const int slot = h * 40 + (g + 1) * (2 * g + (qtb & 3)) + chk;
  const int R0 = qtb * BQ;
  const int NT = 2 * qtb + 2;
  const int kt_beg = chk * CHT;
  const int kt_end = min(kt_beg + CHT, NT);
  const float scale = 0.072168784f;  // 1/sqrt(192)

  // Q A-frags: wave's 16 rows
  const int qrow = R0 + wave * 16 + lane15;
  short8 qf[6];
  const short* qbase = qk + (size_t)qrow * QKVS + h * HD + quad * 8;
#pragma unroll
  for (int kc = 0; kc < 6; ++kc) qf[kc] = *(const short8*)(qbase + kc * 32);

  // staging descriptors (XOR-swizzled), 512 threads: K 3/thread, V 2/thread
  const short* kb = qk + QKD;
  int lKoff[3]; const short* gK[3];
#pragma unroll
  for (int i = 0; i < 3; ++i) {
    int id = i * 512 + tid;
    int row = id / 24, cX = id - row * 24;
    int ch = cX ^ (row & 7);
    lKoff[i] = id * 8;
    gK[i] = kb + (size_t)row * QKVS + h * HD + ch * 8;
  }
  const short* gV[2]; short* lV[2];
#pragma unroll
  for (int i = 0; i < 2; ++i) {
    int id = i * 512 + tid;
    int row = id >> 3, cX = id & 7;
    int ch = cX ^ (row & 7);
    lV[i] = &Vt[id * 8];
    gV[i] = vtb + (size_t)h * VDIM * SEQ + (size_t)row * SEQ + ch * 8;
  }

  f32x4 oacc[8];
#pragma unroll
  for (int i = 0; i < 8; ++i) oacc[i] = (f32x4)(0.f);
  float lsum[4] = {0.f, 0.f, 0.f, 0.f};

  short* pw = &Ps[wave * 16 * PSTR];

  for (int kt = kt_beg; kt < kt_end; ++kt) {
    const int t0 = kt * BT;
    __syncthreads();
#pragma unroll
    for (int i = 0; i < 3; ++i) gload16(gK[i] + (size_t)t0 * QKVS, &Ks[lKoff[i]]);
#pragma unroll
    for (int i = 0; i < 2; ++i) gload16(gV[i] + t0, lV[i]);
    __syncthreads();

    // S = Q K^T
    f32x4 sacc[4];
    __builtin_amdgcn_s_setprio(1);
#pragma unroll
    for (int c = 0; c < 4; ++c) {
      sacc[c] = (f32x4)(0.f);
      const int row = c * 16 + lane15;
#pragma unroll
      for (int kc = 0; kc < 6; ++kc) {
        int cX = (4 * kc + quad) ^ (lane15 & 7);
        short8 kf = *(const short8*)&Ks[row * 192 + cX * 8];
        sacc[c] = __builtin_amdgcn_mfma_f32_16x16x32_bf16(qf[kc], kf, sacc[c], 0, 0, 0);
      }
    }
    __builtin_amdgcn_s_setprio(0);

    if (kt >= 2 * qtb) {  // tiles possibly crossing the diagonal
#pragma unroll
      for (int c = 0; c < 4; ++c)
#pragma unroll
        for (int r = 0; r < 4; ++r) {
          int tg = t0 + c * 16 + lane15;
          int qg = R0 + wave * 16 + quad * 4 + r;
          if (tg > qg) sacc[c][r] = -1e30f;
        }
    }

    // P = exp(S*scale - MFIX); partial row sums; stage P bf16 (wave-local)
#pragma unroll
    for (int c = 0; c < 4; ++c)
#pragma unroll
      for (int r = 0; r < 4; ++r) {
        float p = __expf(sacc[c][r] * scale - MFIX);
        lsum[r] += p;
        pw[(quad * 4 + r) * PSTR + c * 16 + lane15] = f2bf(p);
      }

    short8 pf0 = *(const short8*)&pw[lane15 * PSTR + quad * 8];
    short8 pf1 = *(const short8*)&pw[lane15 * PSTR + 32 + quad * 8];
    __builtin_amdgcn_s_setprio(1);
#pragma unroll
    for (int ch = 0; ch < 8; ++ch) {
      const int row = ch * 16 + lane15;
      int cX0 = quad ^ (lane15 & 7);
      int cX1 = (4 + quad) ^ (lane15 & 7);
      short8 vf0 = *(const short8*)&Vt[row * 64 + cX0 * 8];
      short8 vf1 = *(const short8*)&Vt[row * 64 + cX1 * 8];
      oacc[ch] = __builtin_amdgcn_mfma_f32_16x16x32_bf16(pf0, vf0, oacc[ch], 0, 0, 0);
      oacc[ch] = __builtin_amdgcn_mfma_f32_16x16x32_bf16(pf1, vf1, oacc[ch], 0, 0, 0);
    }
    __builtin_amdgcn_s_setprio(0);
  }

  // epilogue: write unnormalized partials ([128][128] per slot)
  short* op = Opart + (size_t)slot * (128 * 128);
#pragma unroll
  for (int ch = 0; ch < 8; ++ch)
#pragma unroll
    for (int r = 0; r < 4; ++r)
      op[(wave * 16 + quad * 4 + r) * 128 + ch * 16 + lane15] = f2bf(oacc[ch][r]);

  float red[4];
#pragma unroll
  for (int r = 0; r < 4; ++r) {
    float s = lsum[r];
    s += __shfl_xor(s, 1, 64);
    s += __shfl_xor(s, 2, 64);
    s += __shfl_xor(s, 4, 64);
    s += __shfl_xor(s, 8, 64);
    red[r] = s;
  }
  if (lane15 == 0) {
#pragma unroll
    for (int r = 0; r < 4; ++r)
      lpart[(size_t)slot * 128 + wave * 16 + quad * 4 + r] = red[r];
  }
}

// ---------------------------------------------------------------------------
// Phase B: sum chunk partials, normalize, write aob (into v-cols of qkv).
// blockIdx.x = qt64 (0..31, 64-row half of a 128-row qt-block), .y = head.
// ---------------------------------------------------------------------------
__global__ __launch_bounds__(256) void attn_combine(
    const short* __restrict__ Opart, const float* __restrict__ lpart,
    short* __restrict__ aob) {   // aob = qkv + 6144, row stride QKVS
  const int qt64 = blockIdx.x, h = blockIdx.y;
  const int qtb = qt64 >> 1;
  const int half = qt64 & 1;
  const int g = qtb >> 2;
  const int nact = g + 1;
  const int base = h * 40 + (g + 1) * (2 * g + (qtb & 3));
  const int tid = threadIdx.x;
  const int row = tid >> 2;            // 0..63
  const int cg = (tid & 3) * 32;

  float acc[32];
#pragma unroll
  for (int e = 0; e < 32; ++e) acc[e] = 0.f;
  float lsum = 0.f;

  for (int c = 0; c < nact; ++c) {
    const short* sp = Opart + (size_t)(base + c) * (128 * 128) +
                      (half * 64 + row) * 128 + cg;
    lsum += lpart[(size_t)(base + c) * 128 + half * 64 + row];
#pragma unroll
    for (int gg = 0; gg < 4; ++gg) {
      short8 vv = *(const short8*)(sp + gg * 8);
#pragma unroll
      for (int e = 0; e < 8; ++e) acc[gg * 8 + e] += bf2f((unsigned short)vv[e]);
    }
  }

  float inv = 1.f / lsum;
#pragma unroll
  for (int gg = 0; gg < 4; ++gg) {
    short8 ov;
#pragma unroll
    for (int e = 0; e < 8; ++e) ov[e] = f2bf(acc[gg * 8 + e] * inv);
    *(short8*)(aob + (size_t)(qt64 * 64 + row) * QKVS + h * 128 + cg + gg * 8) = ov;
  }
}

// ---------------------------------------------------------------------------
// Workspace (bytes), peak 75,497,472 (< proven 79,691,776):
//   [0,        8388608)  xb  -> wo_b (after qkv gemm)
//   [8388608, 41943040)  wqkv -> {vtb@8388608, Opart@16777216 (640x128x128x2
//                        = 20,971,520), lpart@37748736 (640x128x4 = 327,680)}
//   [41943040,75497472)  qkv bf16 [2048][8192]; aob lives in v-cols (6144+)
// ---------------------------------------------------------------------------
extern "C" void kernel_launch(void* const* d_in, const int* in_sizes, int n_in,
                              void* d_out, int out_size, void* d_ws, size_t ws_size,
                              hipStream_t stream) {
  const float* x  = (const float*)d_in[0];
  const float* wq = (const float*)d_in[1];
  const float* wk = (const float*)d_in[2];
  const float* wv = (const float*)d_in[3];
  const float* wo = (const float*)d_in[4];
  const float* fc = (const float*)d_in[5];
  const float* fs = (const float*)d_in[6];

  char* ws8 = (char*)d_ws;
  short* xb    = (short*)(ws8 + 0);
  short* wo_b  = (short*)(ws8 + 0);
  short* wqkv  = (short*)(ws8 + 8388608);
  short* vtb   = (short*)(ws8 + 8388608);
  short* Opart = (short*)(ws8 + 16777216);
  float* lpart = (float*)(ws8 + 37748736);
  short* qkv   = (short*)(ws8 + 41943040);
  float* out   = (float*)d_out;

  const int NX4 = DIM * DIM / 4;
  const int NQKV4 = QKVS * DIM / 4;
  const int ROPE_GRID = (SEQ * NH * 32) / 256;

  bf16_convert<<<(NX4 + 255) / 256, 256, 0, stream>>>(x, xb, NX4);
  conv_wqkv<<<(NQKV4 + 255) / 256, 256, 0, stream>>>(wq, wk, wv, wqkv, NQKV4);

  // fused QKV projection: qkv [2048][8192] via 256^2 8-phase kernel.
  gemm256_bt<<<dim3((QKVS / 256) * (SEQ / 256)), 512, 0, stream>>>(
      xb, wqkv, qkv, DIM, DIM, DIM, QKVS);
  rope_qk<<<ROPE_GRID, 256, 0, stream>>>(qkv, fc, fs);
  vt_bf16<<<dim3(SEQ / 64, VD / 64), 256, 0, stream>>>(qkv + 2 * QKD, vtb);

  // wo convert (xb dead after qkv gemm)
  bf16_convert<<<(NX4 + 255) / 256, 256, 0, stream>>>(wo, wo_b, NX4);

  // split-T attention: grid (8 xcd, 80 chunks) = 640 blocks, 512 threads
  attn_part<<<dim3(8, 80), 512, 0, stream>>>(qkv, vtb, Opart, lpart);
  attn_combine<<<dim3(SEQ / 64, NH), 256, 0, stream>>>(Opart, lpart, qkv + 2 * QKD);

  // output projection (A = aob in v-cols, lda = QKVS)
  gemm_bt<false><<<dim3(DIM / 128, SEQ / 128), 256, 0, stream>>>(
      qkv + 2 * QKD, wo_b, out, DIM, QKVS, DIM, DIM, 1.0f);
}

// Round 6
// 324.891 us; speedup vs baseline: 1.3076x; 1.0144x over previous
//
#include <hip/hip_runtime.h>
#include <hip/hip_bf16.h>
#include <math.h>

#define NH 16
#define NOPE 128
#define ROPE 64
#define VDIM 128
#define HD 192          // HEAD_DIM
#define SEQ 2048
#define DIM 2048
#define QKD (NH * HD)   // 3072
#define VD  (NH * VDIM) // 2048
#define QKVS 8192       // fused q|k|v row stride (shorts): [q 3072][k 3072][v 2048]

typedef __attribute__((ext_vector_type(8))) short short8;   // 8 bf16 = 4 VGPRs
typedef __attribute__((ext_vector_type(4))) short short4v;
typedef __attribute__((ext_vector_type(4))) float f32x4;
typedef unsigned int u32;

// s_waitcnt immediates (gfx9 encoding: vmcnt[3:0]@0, expcnt@4, lgkmcnt@8, vmcnt[5:4]@14)
#define WAIT_VM8  0x0F78   // vmcnt(8)
#define WAIT_VM6  0x0F76   // vmcnt(6)
#define WAIT_VM0  0x0F70   // vmcnt(0)
#define WAIT_LGKM 0xC07F   // lgkmcnt(0), vmcnt/exp no-wait

static __device__ inline short f2bf(float f) {
  union { float f; unsigned u; } v; v.f = f;
  unsigned r = (v.u + 0x7fffu + ((v.u >> 16) & 1u)) >> 16;
  return (short)r;
}
static __device__ inline float bf2f(unsigned short u) {
  union { unsigned u; float f; } v; v.u = ((unsigned)u) << 16;
  return v.f;
}

// async global->LDS, 16B/lane. LDS dest = wave-uniform base + lane*16.
static __device__ __forceinline__ void gload16(const short* g, short* l) {
  __builtin_amdgcn_global_load_lds(
      (const __attribute__((address_space(1))) u32*)g,
      (__attribute__((address_space(3))) u32*)l, 16, 0, 0);
}

// ---------------------------------------------------------------------------
// 256x256 8-phase bf16 GEMM (T3+T4+T5+T1), C = A * B^T.
// R6 change: XCD partition 1Mx32N -> 8Mx4N (footprint 33 -> 12 MB/XCD;
// N-panels XCD-exclusive so B hits HBM once; K-slice hot set 384 KB << L2).
// ---------------------------------------------------------------------------

#define RDA(pp, hh, mh) do { \
  const char* Lb_ = Lsm + ((pp) * 32768) + ((hh) * 16384) + aoff; \
  afr[0] = *(const short8*)(Lb_ + ((mh) * 4096) + 0); \
  afr[1] = *(const short8*)(Lb_ + ((mh) * 4096) + 1024); \
  afr[2] = *(const short8*)(Lb_ + ((mh) * 4096) + 2048); \
  afr[3] = *(const short8*)(Lb_ + ((mh) * 4096) + 3072); \
} while (0)

#define RDB(pp, hh) do { \
  const char* Lb_ = Lsm + 65536 + ((pp) * 32768) + ((hh) * 16384) + boff; \
  bfr[0] = *(const short8*)(Lb_ + 0); \
  bfr[1] = *(const short8*)(Lb_ + 1024); \
  bfr[2] = *(const short8*)(Lb_ + 2048); \
  bfr[3] = *(const short8*)(Lb_ + 3072); \
} while (0)

#define SA(kt, h) do { \
  char* d_ = Lsm + (((kt) & 1) * 32768) + ((h) * 16384) + wv * 1024; \
  gload16(gA0 + (kt) * 64 + (h) * 32, (short*)d_); \
  gload16(gA1 + (kt) * 64 + (h) * 32, (short*)(d_ + 8192)); \
} while (0)

#define SB(kt, h) do { \
  char* d_ = Lsm + 65536 + (((kt) & 1) * 32768) + ((h) * 16384) + wv * 1024; \
  gload16(gB0 + (kt) * 64 + (h) * 32, (short*)d_); \
  gload16(gB1 + (kt) * 64 + (h) * 32, (short*)(d_ + 8192)); \
} while (0)

#define MFMA1(mi, ni) \
  acc[mi][ni] = __builtin_amdgcn_mfma_f32_16x16x32_bf16(afr[(mi) & 3], bfr[ni], acc[mi][ni], 0, 0, 0)

#define MM(mh) do { \
  MFMA1((mh)*4+0, 0); MFMA1((mh)*4+1, 0); MFMA1((mh)*4+2, 0); MFMA1((mh)*4+3, 0); \
  MFMA1((mh)*4+0, 1); MFMA1((mh)*4+1, 1); MFMA1((mh)*4+2, 1); MFMA1((mh)*4+3, 1); \
  MFMA1((mh)*4+0, 2); MFMA1((mh)*4+1, 2); MFMA1((mh)*4+2, 2); MFMA1((mh)*4+3, 2); \
  MFMA1((mh)*4+0, 3); MFMA1((mh)*4+1, 3); MFMA1((mh)*4+2, 3); MFMA1((mh)*4+3, 3); \
} while (0)

#define GBAR() __builtin_amdgcn_s_barrier()
#define GLGKM0() __builtin_amdgcn_s_waitcnt(WAIT_LGKM)
#define GPRIO1() __builtin_amdgcn_s_setprio(1)
#define GPRIO0() __builtin_amdgcn_s_setprio(0)
#define GNOP ((void)0)

#define TILE(pp, S1, S2, S3, S4, VMW) do { \
  RDA(pp, 0, 0); RDB(pp, 0); S1; \
  GBAR(); GLGKM0(); GPRIO1(); MM(0); GPRIO0(); GBAR(); \
  RDA(pp, 0, 1); S2; \
  GBAR(); GLGKM0(); GPRIO1(); MM(1); GPRIO0(); GBAR(); \
  RDA(pp, 1, 0); RDB(pp, 1); S3; \
  GBAR(); GLGKM0(); GPRIO1(); MM(0); GPRIO0(); GBAR(); \
  RDA(pp, 1, 1); S4; \
  GBAR(); GLGKM0(); GPRIO1(); MM(1); GPRIO0(); VMW; GBAR(); \
} while (0)

__global__ __launch_bounds__(512, 2) void gemm256_bt(
    const short* __restrict__ A, const short* __restrict__ B,
    short* __restrict__ C, int K, int lda, int ldb, int ldc) {
  __shared__ __align__(16) char Lsm[131072];

  const int tid = threadIdx.x;
  const int lane = tid & 63;
  const int l15 = lane & 15;
  const int quad = lane >> 4;      // 0..3
  const int wv = tid >> 6;         // 0..7
  const int wr = wv >> 2, wc = wv & 3;

  // 8Mx4N per-XCD partition: xcd = bid%8 owns all 8 M-panels x 4 N-panels.
  // Footprint/XCD = 8*1MB (A) + 4*1MB (B) = 12 MB; K-slice hot set 384 KB.
  const int bid = blockIdx.x;
  const int xcd = bid & 7;
  const int idx = bid >> 3;              // 0..31 within XCD
  const int m0 = (idx & 7) * 256;        // 8 M panels
  const int n0 = (xcd * 4 + (idx >> 3)) * 256;  // 4 N panels per XCD

  const short* gA0 = A + (size_t)(m0 + wv * 16 + l15) * lda + quad * 8;
  const short* gA1 = gA0 + (size_t)128 * lda;
  const short* gB0 = B + (size_t)(n0 + wv * 16 + l15) * ldb + quad * 8;
  const short* gB1 = gB0 + (size_t)128 * ldb;

  const int aoff = wr * 8192 + lane * 16;
  const int boff = wc * 4096 + lane * 16;

  f32x4 acc[8][4];
#pragma unroll
  for (int i = 0; i < 8; ++i)
#pragma unroll
    for (int j = 0; j < 4; ++j) acc[i][j] = (f32x4)(0.f);
  short8 afr[4], bfr[4];

  const int NT = K >> 6;

  SB(0, 0); SA(0, 0); SB(0, 1); SA(0, 1);
  SB(1, 0); SA(1, 0); SB(1, 1);
  __builtin_amdgcn_s_waitcnt(WAIT_VM6);
  GBAR();

  int kt = 0;
  for (; kt + 4 <= NT; kt += 2) {
    TILE(0, SA(kt + 1, 1), SB(kt + 2, 0), SA(kt + 2, 0), SB(kt + 2, 1),
         __builtin_amdgcn_s_waitcnt(WAIT_VM6));
    TILE(1, SA(kt + 2, 1), SB(kt + 3, 0), SA(kt + 3, 0), SB(kt + 3, 1),
         __builtin_amdgcn_s_waitcnt(WAIT_VM6));
  }
  TILE(0, SA(kt + 1, 1), GNOP, GNOP, GNOP, __builtin_amdgcn_s_waitcnt(WAIT_VM0));
  TILE(1, GNOP, GNOP, GNOP, GNOP, GNOP);

#pragma unroll
  for (int m = 0; m < 8; ++m) {
    const size_t rb = (size_t)(m0 + wr * 128 + m * 16 + quad * 4) * ldc +
                      n0 + wc * 64 + l15;
#pragma unroll
    for (int n = 0; n < 4; ++n)
#pragma unroll
      for (int r = 0; r < 4; ++r)
        C[rb + (size_t)r * ldc + n * 16] = f2bf(acc[m][n][r]);
  }
}

// ---------------------------------------------------------------------------
// bf16 MFMA GEMM v2 (128^2): kept for the output projection.
// ---------------------------------------------------------------------------
template <bool BF16OUT>
__global__ __launch_bounds__(256) void gemm_bt(
    const short* __restrict__ A, const short* __restrict__ B,
    void* __restrict__ Cv, int K, int lda, int ldb, int ldc, float oscale) {
  __shared__ __align__(16) short Ls[4][2][4096];

  const int tid = threadIdx.x;
  const int lane = tid & 63;
  const int wave = tid >> 6;
  const int wr = wave >> 1, wc = wave & 1;
  const int lane15 = lane & 15, quad = lane >> 4;
  const int m0 = blockIdx.y * 128, n0 = blockIdx.x * 128;

  const short* gA[4]; const short* gB[4];
#pragma unroll
  for (int i = 0; i < 4; ++i) {
    int gidx = i * 64 + lane;
    int r = gidx >> 2, p = gidx & 3;
    int g = (p ^ ((r >> 1) & 3)) * 8;
    gA[i] = A + (size_t)(m0 + wr * 64 + r) * lda + g;
    gB[i] = B + (size_t)(n0 + wc * 64 + r) * ldb + g;
  }

  f32x4 acc[4][4];
#pragma unroll
  for (int i = 0; i < 4; ++i)
#pragma unroll
    for (int j = 0; j < 4; ++j) acc[i][j] = (f32x4)(0.f);

#pragma unroll
  for (int i = 0; i < 4; ++i) gload16(gA[i], &Ls[wave][0][i * 512]);
#pragma unroll
  for (int i = 0; i < 4; ++i) gload16(gB[i], &Ls[wave][0][2048 + i * 512]);

  const int rsw = (lane15 >> 1) & 3;
  for (int k0 = 0; k0 < K; k0 += 32) {
    const int cur = (k0 >> 5) & 1;
    __builtin_amdgcn_s_waitcnt(WAIT_LGKM);
    if (k0 + 32 < K) {
      const int nxt = cur ^ 1;
#pragma unroll
      for (int i = 0; i < 4; ++i) gload16(gA[i] + k0 + 32, &Ls[wave][nxt][i * 512]);
#pragma unroll
      for (int i = 0; i < 4; ++i) gload16(gB[i] + k0 + 32, &Ls[wave][nxt][2048 + i * 512]);
      __builtin_amdgcn_s_waitcnt(WAIT_VM8);
    } else {
      __builtin_amdgcn_s_waitcnt(WAIT_VM0);
    }
    const short* bufp = &Ls[wave][cur][0];
    short8 af[4], bfv[4];
#pragma unroll
    for (int i = 0; i < 4; ++i)
      af[i] = *(const short8*)&bufp[(i * 16 + lane15) * 32 + (quad ^ rsw) * 8];
#pragma unroll
    for (int j = 0; j < 4; ++j)
      bfv[j] = *(const short8*)&bufp[2048 + (j * 16 + lane15) * 32 + (quad ^ rsw) * 8];
#pragma unroll
    for (int i = 0; i < 4; ++i)
#pragma unroll
      for (int j = 0; j < 4; ++j)
        acc[i][j] = __builtin_amdgcn_mfma_f32_16x16x32_bf16(af[i], bfv[j], acc[i][j], 0, 0, 0);
  }

#pragma unroll
  for (int i = 0; i < 4; ++i)
#pragma unroll
    for (int j = 0; j < 4; ++j)
#pragma unroll
      for (int r = 0; r < 4; ++r) {
        size_t idx = (size_t)(m0 + wr * 64 + i * 16 + quad * 4 + r) * ldc +
                     n0 + wc * 64 + j * 16 + lane15;
        if (BF16OUT)
          ((short*)Cv)[idx] = f2bf(acc[i][j][r] * oscale);
        else
          ((float*)Cv)[idx] = acc[i][j][r];
      }
}

// ---------------------------------------------------------------------------
// RoPE in-place on fused qkv bf16 [SEQ][QKVS].
// ---------------------------------------------------------------------------
__global__ __launch_bounds__(256) void rope_qk(
    short* __restrict__ qk, const float* __restrict__ cosf, const float* __restrict__ sinf) {
  int idx = blockIdx.x * blockDim.x + threadIdx.x;
  int j = idx & 31;
  int h = (idx >> 5) & (NH - 1);
  int s = idx >> 9;
  if (s >= SEQ) return;

  float c = cosf[s * 32 + j];
  float sn = sinf[s * 32 + j];
  size_t rowb = (size_t)s * QKVS + h * HD + NOPE + 2 * j;

  u32* pq = (u32*)(qk + rowb);
  u32 w = *pq;
  float a = bf2f((unsigned short)(w & 0xffff));
  float b = bf2f((unsigned short)(w >> 16));
  *pq = (u32)(unsigned short)f2bf(a * c - b * sn) |
        ((u32)(unsigned short)f2bf(a * sn + b * c) << 16);

  u32* pk = (u32*)(qk + rowb + QKD);
  w = *pk;
  a = bf2f((unsigned short)(w & 0xffff));
  b = bf2f((unsigned short)(w >> 16));
  *pk = (u32)(unsigned short)f2bf(a * c - b * sn) |
        ((u32)(unsigned short)f2bf(a * sn + b * c) << 16);
}

// ---------------------------------------------------------------------------
// Converts.
// ---------------------------------------------------------------------------
__global__ __launch_bounds__(256) void bf16_convert(
    const float* __restrict__ in, short* __restrict__ out, int n4) {
  int i = blockIdx.x * 256 + threadIdx.x;
  if (i >= n4) return;
  float4 f = ((const float4*)in)[i];
  short4v o;
  o.x = f2bf(f.x); o.y = f2bf(f.y); o.z = f2bf(f.z); o.w = f2bf(f.w);
  ((short4v*)out)[i] = o;
}

__global__ __launch_bounds__(256) void conv_wqkv(
    const float* __restrict__ wq, const float* __restrict__ wk,
    const float* __restrict__ wv, short* __restrict__ wqkv, int n4) {
  int i = blockIdx.x * 256 + threadIdx.x;
  if (i >= n4) return;
  int row = i >> 9;
  float4 f;
  if (row < QKD) f = ((const float4*)wq)[i];
  else if (row < 2 * QKD) f = ((const float4*)wk)[i - QKD * (DIM / 4)];
  else f = ((const float4*)wv)[i - 2 * QKD * (DIM / 4)];
  short4v o;
  o.x = f2bf(f.x); o.y = f2bf(f.y); o.z = f2bf(f.z); o.w = f2bf(f.w);
  ((short4v*)wqkv)[i] = o;
}

// ---------------------------------------------------------------------------
// v bf16 -> vtb bf16 [h][d][t] transpose.
// ---------------------------------------------------------------------------
__global__ __launch_bounds__(256) void vt_bf16(
    const short* __restrict__ vb, short* __restrict__ vtb) {
  __shared__ short tile[64][74];
  const int t0 = blockIdx.x * 64;
  const int c0 = blockIdx.y * 64;
  const int tid = threadIdx.x;
#pragma unroll
  for (int i = 0; i < 16; ++i) {
    int idx = i * 256 + tid;
    int r = idx >> 6, c = idx & 63;
    tile[r][c] = vb[(size_t)(t0 + r) * QKVS + c0 + c];
  }
  __syncthreads();
  const int h = c0 >> 7;
  const int dbase = c0 & 127;
#pragma unroll
  for (int i = 0; i < 16; ++i) {
    int idx = i * 256 + tid;
    int d = idx >> 6, t = idx & 63;
    vtb[(size_t)h * VDIM * SEQ + (size_t)(dbase + d) * SEQ + t0 + t] = tile[t][d];
  }
}

// ---------------------------------------------------------------------------
// Split-T flash attention v4 (unchanged from R5): BQ=128 via 8 waves.
// LDS: 24576 (K) + 16384 (V) + 19456 (Ps) = 60416 -> 2 blocks/CU.
// ---------------------------------------------------------------------------
#define BQ 128
#define BT 64
#define CHT 8
#define PSTR 76
#define MFIX 8.0f

__global__ __launch_bounds__(512, 4) void attn_part(
    const short* __restrict__ qk,   // [SEQ][QKVS] bf16
    const short* __restrict__ vtb,  // [NH][VDIM][SEQ] bf16
    short* __restrict__ Opart,      // [640][128][128] bf16
    float* __restrict__ lpart)      // [640][128] fp32
{
  __shared__ __align__(16) short Ks[BT * 192];      // 24576 B
  __shared__ __align__(16) short Vt[VDIM * BT];     // 16384 B
  __shared__ __align__(16) short Ps[8 * 16 * PSTR]; // 19456 B

  // decode: xcd owns heads {xcd, xcd+8}; heavy qt-blocks first.
  const int xcd = blockIdx.x;          // 0..7
  const int i0 = blockIdx.y;           // 0..79
  const int h = xcd + ((i0 >= 40) ? 8 : 0);
  int jj = (i0 >= 40) ? (i0 - 40) : i0;  // 0..39
  int qtb = 15;
  while (jj >= (qtb >> 2) + 1) { jj -= (qtb >> 2) + 1; --qtb; }
  const int chk = jj;                   // 0..(qtb>>2)

  const int tid = threadIdx.x;
  const int wave = tid >> 6;            // 0..7
  const int lane = tid & 63;
  const int lane15 = lane & 15;
  const int quad = lane >> 4;
  const int g = qtb >> 2;
  const int slot = h * 40 + (g + 1) * (2 * g + (qtb & 3)) + chk;
  const int R0 = qtb * BQ;
  const int NT = 2 * qtb + 2;
  const int kt_beg = chk * CHT;
  const int kt_end = min(kt_beg + CHT, NT);
  const float scale = 0.072168784f;  // 1/sqrt(192)

  // Q A-frags: wave's 16 rows
  const int qrow = R0 + wave * 16 + lane15;
  short8 qf[6];
  const short* qbase = qk + (size_t)qrow * QKVS + h * HD + quad * 8;
#pragma unroll
  for (int kc = 0; kc < 6; ++kc) qf[kc] = *(const short8*)(qbase + kc * 32);

  // staging descriptors (XOR-swizzled), 512 threads: K 3/thread, V 2/thread
  const short* kb = qk + QKD;
  int lKoff[3]; const short* gK[3];
#pragma unroll
  for (int i = 0; i < 3; ++i) {
    int id = i * 512 + tid;
    int row = id / 24, cX = id - row * 24;
    int ch = cX ^ (row & 7);
    lKoff[i] = id * 8;
    gK[i] = kb + (size_t)row * QKVS + h * HD + ch * 8;
  }
  const short* gV[2]; short* lV[2];
#pragma unroll
  for (int i = 0; i < 2; ++i) {
    int id = i * 512 + tid;
    int row = id >> 3, cX = id & 7;
    int ch = cX ^ (row & 7);
    lV[i] = &Vt[id * 8];
    gV[i] = vtb + (size_t)h * VDIM * SEQ + (size_t)row * SEQ + ch * 8;
  }

  f32x4 oacc[8];
#pragma unroll
  for (int i = 0; i < 8; ++i) oacc[i] = (f32x4)(0.f);
  float lsum[4] = {0.f, 0.f, 0.f, 0.f};

  short* pw = &Ps[wave * 16 * PSTR];

  for (int kt = kt_beg; kt < kt_end; ++kt) {
    const int t0 = kt * BT;
    __syncthreads();
#pragma unroll
    for (int i = 0; i < 3; ++i) gload16(gK[i] + (size_t)t0 * QKVS, &Ks[lKoff[i]]);
#pragma unroll
    for (int i = 0; i < 2; ++i) gload16(gV[i] + t0, lV[i]);
    __syncthreads();

    // S = Q K^T
    f32x4 sacc[4];
    __builtin_amdgcn_s_setprio(1);
#pragma unroll
    for (int c = 0; c < 4; ++c) {
      sacc[c] = (f32x4)(0.f);
      const int row = c * 16 + lane15;
#pragma unroll
      for (int kc = 0; kc < 6; ++kc) {
        int cX = (4 * kc + quad) ^ (lane15 & 7);
        short8 kf = *(const short8*)&Ks[row * 192 + cX * 8];
        sacc[c] = __builtin_amdgcn_mfma_f32_16x16x32_bf16(qf[kc], kf, sacc[c], 0, 0, 0);
      }
    }
    __builtin_amdgcn_s_setprio(0);

    if (kt >= 2 * qtb) {  // tiles possibly crossing the diagonal
#pragma unroll
      for (int c = 0; c < 4; ++c)
#pragma unroll
        for (int r = 0; r < 4; ++r) {
          int tg = t0 + c * 16 + lane15;
          int qg = R0 + wave * 16 + quad * 4 + r;
          if (tg > qg) sacc[c][r] = -1e30f;
        }
    }

    // P = exp(S*scale - MFIX); partial row sums; stage P bf16 (wave-local)
#pragma unroll
    for (int c = 0; c < 4; ++c)
#pragma unroll
      for (int r = 0; r < 4; ++r) {
        float p = __expf(sacc[c][r] * scale - MFIX);
        lsum[r] += p;
        pw[(quad * 4 + r) * PSTR + c * 16 + lane15] = f2bf(p);
      }

    short8 pf0 = *(const short8*)&pw[lane15 * PSTR + quad * 8];
    short8 pf1 = *(const short8*)&pw[lane15 * PSTR + 32 + quad * 8];
    __builtin_amdgcn_s_setprio(1);
#pragma unroll
    for (int ch = 0; ch < 8; ++ch) {
      const int row = ch * 16 + lane15;
      int cX0 = quad ^ (lane15 & 7);
      int cX1 = (4 + quad) ^ (lane15 & 7);
      short8 vf0 = *(const short8*)&Vt[row * 64 + cX0 * 8];
      short8 vf1 = *(const short8*)&Vt[row * 64 + cX1 * 8];
      oacc[ch] = __builtin_amdgcn_mfma_f32_16x16x32_bf16(pf0, vf0, oacc[ch], 0, 0, 0);
      oacc[ch] = __builtin_amdgcn_mfma_f32_16x16x32_bf16(pf1, vf1, oacc[ch], 0, 0, 0);
    }
    __builtin_amdgcn_s_setprio(0);
  }

  // epilogue: write unnormalized partials ([128][128] per slot)
  short* op = Opart + (size_t)slot * (128 * 128);
#pragma unroll
  for (int ch = 0; ch < 8; ++ch)
#pragma unroll
    for (int r = 0; r < 4; ++r)
      op[(wave * 16 + quad * 4 + r) * 128 + ch * 16 + lane15] = f2bf(oacc[ch][r]);

  float red[4];
#pragma unroll
  for (int r = 0; r < 4; ++r) {
    float s = lsum[r];
    s += __shfl_xor(s, 1, 64);
    s += __shfl_xor(s, 2, 64);
    s += __shfl_xor(s, 4, 64);
    s += __shfl_xor(s, 8, 64);
    red[r] = s;
  }
  if (lane15 == 0) {
#pragma unroll
    for (int r = 0; r < 4; ++r)
      lpart[(size_t)slot * 128 + wave * 16 + quad * 4 + r] = red[r];
  }
}

// ---------------------------------------------------------------------------
// Phase B: sum chunk partials, normalize, write aob (into v-cols of qkv).
// blockIdx.x = qt64 (0..31, 64-row half of a 128-row qt-block), .y = head.
// ---------------------------------------------------------------------------
__global__ __launch_bounds__(256) void attn_combine(
    const short* __restrict__ Opart, const float* __restrict__ lpart,
    short* __restrict__ aob) {   // aob = qkv + 6144, row stride QKVS
  const int qt64 = blockIdx.x, h = blockIdx.y;
  const int qtb = qt64 >> 1;
  const int half = qt64 & 1;
  const int g = qtb >> 2;
  const int nact = g + 1;
  const int base = h * 40 + (g + 1) * (2 * g + (qtb & 3));
  const int tid = threadIdx.x;
  const int row = tid >> 2;            // 0..63
  const int cg = (tid & 3) * 32;

  float acc[32];
#pragma unroll
  for (int e = 0; e < 32; ++e) acc[e] = 0.f;
  float lsum = 0.f;

  for (int c = 0; c < nact; ++c) {
    const short* sp = Opart + (size_t)(base + c) * (128 * 128) +
                      (half * 64 + row) * 128 + cg;
    lsum += lpart[(size_t)(base + c) * 128 + half * 64 + row];
#pragma unroll
    for (int gg = 0; gg < 4; ++gg) {
      short8 vv = *(const short8*)(sp + gg * 8);
#pragma unroll
      for (int e = 0; e < 8; ++e) acc[gg * 8 + e] += bf2f((unsigned short)vv[e]);
    }
  }

  float inv = 1.f / lsum;
#pragma unroll
  for (int gg = 0; gg < 4; ++gg) {
    short8 ov;
#pragma unroll
    for (int e = 0; e < 8; ++e) ov[e] = f2bf(acc[gg * 8 + e] * inv);
    *(short8*)(aob + (size_t)(qt64 * 64 + row) * QKVS + h * 128 + cg + gg * 8) = ov;
  }
}

// ---------------------------------------------------------------------------
// Workspace (bytes), peak 75,497,472 (< proven 79,691,776):
//   [0,        8388608)  xb  -> wo_b (after qkv gemm)
//   [8388608, 41943040)  wqkv -> {vtb@8388608, Opart@16777216 (640x128x128x2
//                        = 20,971,520), lpart@37748736 (640x128x4 = 327,680)}
//   [41943040,75497472)  qkv bf16 [2048][8192]; aob lives in v-cols (6144+)
// ---------------------------------------------------------------------------
extern "C" void kernel_launch(void* const* d_in, const int* in_sizes, int n_in,
                              void* d_out, int out_size, void* d_ws, size_t ws_size,
                              hipStream_t stream) {
  const float* x  = (const float*)d_in[0];
  const float* wq = (const float*)d_in[1];
  const float* wk = (const float*)d_in[2];
  const float* wv = (const float*)d_in[3];
  const float* wo = (const float*)d_in[4];
  const float* fc = (const float*)d_in[5];
  const float* fs = (const float*)d_in[6];

  char* ws8 = (char*)d_ws;
  short* xb    = (short*)(ws8 + 0);
  short* wo_b  = (short*)(ws8 + 0);
  short* wqkv  = (short*)(ws8 + 8388608);
  short* vtb   = (short*)(ws8 + 8388608);
  short* Opart = (short*)(ws8 + 16777216);
  float* lpart = (float*)(ws8 + 37748736);
  short* qkv   = (short*)(ws8 + 41943040);
  float* out   = (float*)d_out;

  const int NX4 = DIM * DIM / 4;
  const int NQKV4 = QKVS * DIM / 4;
  const int ROPE_GRID = (SEQ * NH * 32) / 256;

  bf16_convert<<<(NX4 + 255) / 256, 256, 0, stream>>>(x, xb, NX4);
  conv_wqkv<<<(NQKV4 + 255) / 256, 256, 0, stream>>>(wq, wk, wv, wqkv, NQKV4);

  // fused QKV projection: qkv [2048][8192] via 256^2 8-phase kernel.
  gemm256_bt<<<dim3((QKVS / 256) * (SEQ / 256)), 512, 0, stream>>>(
      xb, wqkv, qkv, DIM, DIM, DIM, QKVS);
  rope_qk<<<ROPE_GRID, 256, 0, stream>>>(qkv, fc, fs);
  vt_bf16<<<dim3(SEQ / 64, VD / 64), 256, 0, stream>>>(qkv + 2 * QKD, vtb);

  // wo convert (xb dead after qkv gemm)
  bf16_convert<<<(NX4 + 255) / 256, 256, 0, stream>>>(wo, wo_b, NX4);

  // split-T attention: grid (8 xcd, 80 chunks) = 640 blocks, 512 threads
  attn_part<<<dim3(8, 80), 512, 0, stream>>>(qkv, vtb, Opart, lpart);
  attn_combine<<<dim3(SEQ / 64, NH), 256, 0, stream>>>(Opart, lpart, qkv + 2 * QKD);

  // output projection (A = aob in v-cols, lda = QKVS)
  gemm_bt<false><<<dim3(DIM / 128, SEQ / 128), 256, 0, stream>>>(
      qkv + 2 * QKD, wo_b, out, DIM, QKVS, DIM, DIM, 1.0f);
}